// Round 13
// baseline (36.265 us; speedup 1.0000x reference)
//
#include <hip/hip_runtime.h>
#include <hip/hip_bf16.h>
#include <stdint.h>

#define N_NODES 4096
#define BATCH 2

typedef __attribute__((ext_vector_type(8))) short short8v;
typedef __attribute__((ext_vector_type(4))) unsigned short ushort4v;
typedef __attribute__((ext_vector_type(4))) float f32x4;

#define GLL16(gsrc, ldst) \
    __builtin_amdgcn_global_load_lds((const __attribute__((address_space(1))) void*)(gsrc), \
                                     (__attribute__((address_space(3))) void*)(ldst), 16, 0, 0)

static __device__ inline unsigned short f2bf_rn(float x) {
    unsigned u = __float_as_uint(x);
    unsigned r = (u + 0x7FFFu + ((u >> 16) & 1u)) >> 16;
    return (unsigned short)r;
}
static __device__ inline float bf2f(unsigned short b) {
    return __uint_as_float(((unsigned)b) << 16);
}
static __device__ inline float rl(float v, int k) {   // wave-uniform broadcast
    return __uint_as_float(__builtin_amdgcn_readlane(__float_as_uint(v), k));
}

// ---------------------------------------------------------------------------
// K1: norm only -> split-bf16 ne (adj's sole prerequisite). 16 rows/block.
// ---------------------------------------------------------------------------
__global__ __launch_bounds__(256) void norm_kernel(
        const float* __restrict__ emb,
        unsigned short* __restrict__ ne_hi, unsigned short* __restrict__ ne_lo) {
    int t = threadIdx.x;
    int row = blockIdx.x * 16 + (t >> 4);
    int l16 = t & 15;
    float4 v = *(const float4*)&emb[(size_t)row * 64 + l16 * 4];
    float s = v.x * v.x + v.y * v.y + v.z * v.z + v.w * v.w;
#pragma unroll
    for (int m = 8; m >= 1; m >>= 1) s += __shfl_xor(s, m);
    float inv = 1.f / sqrtf(s);
    float n0 = v.x * inv, n1 = v.y * inv, n2 = v.z * inv, n3 = v.w * inv;
    ushort4v h = {f2bf_rn(n0), f2bf_rn(n1), f2bf_rn(n2), f2bf_rn(n3)};
    ushort4v lo = {f2bf_rn(n0 - bf2f(h.x)), f2bf_rn(n1 - bf2f(h.y)),
                   f2bf_rn(n2 - bf2f(h.z)), f2bf_rn(n3 - bf2f(h.w))};
    *(ushort4v*)&ne_hi[(size_t)row * 64 + l16 * 4] = h;
    *(ushort4v*)&ne_lo[(size_t)row * 64 + l16 * 4] = lo;
}

// ---------------------------------------------------------------------------
// K2 fat kernel: blocks [0,256) feat1; blocks [256,1280) adjacency.
// Adj: BK=32 two-step, 32 KiB LDS, PLANE-MAJOR layout LDS[slot][row][8sh]
// -> ds_read_b128 is 256B-contiguous per 16-lane group: conflict-free.
// Staging via global_load_lds: wave w fills plane w (linear LDS dest).
// ---------------------------------------------------------------------------
__global__ __launch_bounds__(256) void k2_kernel(
        const unsigned short* __restrict__ hi, const unsigned short* __restrict__ lo,
        unsigned long long* __restrict__ mask,
        const float* __restrict__ x, const float* __restrict__ Wp,
        const float* __restrict__ bp, const float* __restrict__ W1,
        const float* __restrict__ a1s, const float* __restrict__ a1d,
        float* __restrict__ h1out, float* __restrict__ ssrc, float* __restrict__ sdst) {
    __shared__ unsigned short Ah[4096];   // [4 planes][128 rows][8 shorts]
    __shared__ unsigned short Al[4096];
    __shared__ unsigned short Bh[4096];
    __shared__ unsigned short Bl[4096];
    int t = threadIdx.x;
    int w = t >> 6, l = t & 63;

    if (blockIdx.x < 256) {
        // ================= feat1: proj + mm1 + scores1 (R5-verified) =======
        int b = blockIdx.x;
        int row0 = b * 32 + w * 8;

        float xv[8];
#pragma unroll
        for (int r = 0; r < 8; ++r) xv[r] = x[(size_t)(row0 + r) * 16 + (l & 15)];

        float h0[8];
        float bpv = bp[l];
#pragma unroll
        for (int r = 0; r < 8; ++r) h0[r] = bpv;
#pragma unroll
        for (int k = 0; k < 16; ++k) {
            float wk = Wp[k * 64 + l];
#pragma unroll
            for (int r = 0; r < 8; ++r) h0[r] += rl(xv[r], k) * wk;
        }

        float h1[8] = {0.f, 0.f, 0.f, 0.f, 0.f, 0.f, 0.f, 0.f};
#pragma unroll
        for (int k = 0; k < 64; ++k) {
            float wk = W1[k * 64 + l];
#pragma unroll
            for (int r = 0; r < 8; ++r) h1[r] += rl(h0[r], k) * wk;
        }

        float as_ = a1s[l], ad_ = a1d[l];
#pragma unroll
        for (int r = 0; r < 8; ++r) {
            h1out[(size_t)(row0 + r) * 64 + l] = h1[r];
            float ps = h1[r] * as_, pd = h1[r] * ad_;
#pragma unroll
            for (int m = 8; m >= 1; m >>= 1) {
                ps += __shfl_xor(ps, m);
                pd += __shfl_xor(pd, m);
            }
            if ((l & 15) == 0) {
                ssrc[(size_t)(row0 + r) * 4 + (l >> 4)] = ps;
                sdst[(size_t)(row0 + r) * 4 + (l >> 4)] = pd;
            }
        }
        return;
    }

    // ================= adjacency =================
    int tile = blockIdx.x - 256;
    int bi = tile >> 5, bj = tile & 31;
    int i0 = bi * 128, j0 = bj * 128;

    int fr = l & 15;
    int s0 = l >> 4;                     // k-slot plane 0..3 (k = s0*8)

    f32x4 acc[2][8];
#pragma unroll
    for (int rt = 0; rt < 2; ++rt)
#pragma unroll
        for (int js = 0; js < 8; ++js) acc[rt][js] = (f32x4){0.f, 0.f, 0.f, 0.f};

#pragma unroll 1
    for (int ks = 0; ks < 2; ++ks) {
        // ---- stage: wave w fills plane w of each buffer (2x 64-row chunks)
#pragma unroll
        for (int c = 0; c < 2; ++c) {
            size_t ga = (size_t)(i0 + c * 64 + l) * 64 + ks * 32 + w * 8;
            size_t gb = (size_t)(j0 + c * 64 + l) * 64 + ks * 32 + w * 8;
            int dst = w * 1024 + c * 512;          // shorts
            GLL16(hi + ga, &Ah[dst]);
            GLL16(lo + ga, &Al[dst]);
            GLL16(hi + gb, &Bh[dst]);
            GLL16(lo + gb, &Bl[dst]);
        }
        __syncthreads();

        short8v aH[2], aL[2];
#pragma unroll
        for (int rt = 0; rt < 2; ++rt) {
            int abase = s0 * 1024 + (w * 32 + rt * 16 + fr) * 8;
            aH[rt] = *(const short8v*)&Ah[abase];
            aL[rt] = *(const short8v*)&Al[abase];
        }

#pragma unroll
        for (int js = 0; js < 8; ++js) {
            int bbase = s0 * 1024 + (js * 16 + fr) * 8;
            short8v bH = *(const short8v*)&Bh[bbase];
            short8v bL = *(const short8v*)&Bl[bbase];
#pragma unroll
            for (int rt = 0; rt < 2; ++rt) {
                f32x4 a = acc[rt][js];
                a = __builtin_amdgcn_mfma_f32_16x16x32_bf16(aH[rt], bH, a, 0, 0, 0);
                a = __builtin_amdgcn_mfma_f32_16x16x32_bf16(aH[rt], bL, a, 0, 0, 0);
                a = __builtin_amdgcn_mfma_f32_16x16x32_bf16(aL[rt], bH, a, 0, 0, 0);
                acc[rt][js] = a;
            }
        }
        if (ks == 0) __syncthreads();   // LDS reuse guard before restage
    }

    // ---- pack to bitmask. C/D layout: col=lane&15, row=(lane>>4)*4+reg ----
    int shift = ((l & 15) >> 2) * 16;
    int r = l & 3;
#pragma unroll
    for (int rt = 0; rt < 2; ++rt) {
#pragma unroll
        for (int ws_ = 0; ws_ < 2; ++ws_) {
            unsigned long long w64 = 0;
#pragma unroll
            for (int js2 = 0; js2 < 4; ++js2) {
                f32x4 a = acc[rt][ws_ * 4 + js2];
                unsigned long long c0 = __ballot(a[0] > 0.5f);
                unsigned long long c1 = __ballot(a[1] > 0.5f);
                unsigned long long c2 = __ballot(a[2] > 0.5f);
                unsigned long long c3 = __ballot(a[3] > 0.5f);
                unsigned long long sel = r == 0 ? c0 : r == 1 ? c1 : r == 2 ? c2 : c3;
                w64 |= ((sel >> shift) & 0xFFFFULL) << (js2 * 16);
            }
            if (l < 16)
                mask[(size_t)(i0 + w * 32 + rt * 16 + l) * 64 + bj * 2 + ws_] = w64;
        }
    }
}

// ---------------------------------------------------------------------------
// K3 (R11-verified): agg1(+bias+ReLU)+mm2+scores2, batch-paired.
// ---------------------------------------------------------------------------
__global__ __launch_bounds__(256) void agg1_fused_kernel(
        const float* __restrict__ h1, const float* __restrict__ ssrc,
        const float* __restrict__ sdst, const unsigned long long* __restrict__ mask,
        const float* __restrict__ b1, const float* __restrict__ W2,
        const float* __restrict__ a2s, const float* __restrict__ a2d,
        float* __restrict__ h2out, float* __restrict__ s2s, float* __restrict__ s2d) {
    int i = blockIdx.x * 4 + (threadIdx.x >> 6);   // node 0..4095
    int t = threadIdx.x & 63;
    int hh = t >> 4;

    float sdA = sdst[(size_t)i * 4 + hh];
    float sdB = sdst[(size_t)(i + N_NODES) * 4 + hh];
    unsigned long long myword = mask[(size_t)i * 64 + t];

    float mA = -1e30f, dA = 0.f, aA = 0.f;
    float mB = -1e30f, dB = 0.f, aB = 0.f;
    unsigned long long nz = __ballot(myword != 0ULL);
    while (nz) {
        int lw = __ffsll(nz) - 1;
        nz &= nz - 1;
        unsigned long long wbits = __shfl(myword, lw);
        while (wbits) {
            int bpos = __ffsll(wbits) - 1;
            wbits &= wbits - 1;
            int j = (lw << 6) + bpos;
            float ssA = ssrc[(size_t)j * 4 + hh];
            float ssB = ssrc[(size_t)(j + N_NODES) * 4 + hh];
            float hvA = h1[(size_t)j * 64 + t];
            float hvB = h1[(size_t)(j + N_NODES) * 64 + t];
            float e = sdA + ssA;
            e = e > 0.f ? e : 0.2f * e;
            float mn = fmaxf(mA, e);
            float cf = __expf(mA - mn);
            float wg = __expf(e - mn);
            dA = dA * cf + wg;
            aA = aA * cf + wg * hvA;
            mA = mn;
            e = sdB + ssB;
            e = e > 0.f ? e : 0.2f * e;
            mn = fmaxf(mB, e);
            cf = __expf(mB - mn);
            wg = __expf(e - mn);
            dB = dB * cf + wg;
            aB = aB * cf + wg * hvB;
            mB = mn;
        }
    }
    float b1v = b1[t];
    float oA = fmaxf(aA / dA + b1v, 0.f);
    float oB = fmaxf(aB / dB + b1v, 0.f);

    // mm2 for both rows (lanes 32..63 duplicate 0..31)
    int l2 = t & 31;
    float acc2A = 0.f, acc2B = 0.f;
#pragma unroll
    for (int k = 0; k < 64; ++k) {
        float wk = W2[k * 32 + l2];
        acc2A += rl(oA, k) * wk;
        acc2B += rl(oB, k) * wk;
    }

    float a2sv = a2s[l2], a2dv = a2d[l2];
    float psA = acc2A * a2sv, pdA = acc2A * a2dv;
    float psB = acc2B * a2sv, pdB = acc2B * a2dv;
#pragma unroll
    for (int mm = 4; mm >= 1; mm >>= 1) {
        psA += __shfl_xor(psA, mm);
        pdA += __shfl_xor(pdA, mm);
        psB += __shfl_xor(psB, mm);
        pdB += __shfl_xor(pdB, mm);
    }
    if (t < 32) {
        h2out[(size_t)i * 32 + t] = acc2A;
        h2out[(size_t)(i + N_NODES) * 32 + t] = acc2B;
        if ((t & 7) == 0) {
            s2s[(size_t)i * 4 + (t >> 3)] = psA;
            s2d[(size_t)i * 4 + (t >> 3)] = pdA;
            s2s[(size_t)(i + N_NODES) * 4 + (t >> 3)] = psB;
            s2d[(size_t)(i + N_NODES) * 4 + (t >> 3)] = pdB;
        }
    }
}

// ---------------------------------------------------------------------------
// K4 (R11-verified): agg2, batch-paired -> d_out.
// ---------------------------------------------------------------------------
__global__ __launch_bounds__(256) void agg2_kernel(
        const float* __restrict__ hfeat, const float* __restrict__ ssrc,
        const float* __restrict__ sdst, const unsigned long long* __restrict__ mask,
        const float* __restrict__ bias, float* __restrict__ out) {
    int i = blockIdx.x * 4 + (threadIdx.x >> 6);   // node 0..4095
    int t = threadIdx.x & 63;
    int tt = t & 31;
    int hh = tt >> 3;

    float sdA = sdst[(size_t)i * 4 + hh];
    float sdB = sdst[(size_t)(i + N_NODES) * 4 + hh];
    unsigned long long myword = mask[(size_t)i * 64 + t];

    float mA = -1e30f, dA = 0.f, aA = 0.f;
    float mB = -1e30f, dB = 0.f, aB = 0.f;
    unsigned long long nz = __ballot(myword != 0ULL);
    while (nz) {
        int lw = __ffsll(nz) - 1;
        nz &= nz - 1;
        unsigned long long wbits = __shfl(myword, lw);
        while (wbits) {
            int bpos = __ffsll(wbits) - 1;
            wbits &= wbits - 1;
            int j = (lw << 6) + bpos;
            float ssA = ssrc[(size_t)j * 4 + hh];
            float ssB = ssrc[(size_t)(j + N_NODES) * 4 + hh];
            float hvA = hfeat[(size_t)j * 32 + tt];
            float hvB = hfeat[(size_t)(j + N_NODES) * 32 + tt];
            float e = sdA + ssA;
            e = e > 0.f ? e : 0.2f * e;
            float mn = fmaxf(mA, e);
            float cf = __expf(mA - mn);
            float wg = __expf(e - mn);
            dA = dA * cf + wg;
            aA = aA * cf + wg * hvA;
            mA = mn;
            e = sdB + ssB;
            e = e > 0.f ? e : 0.2f * e;
            mn = fmaxf(mB, e);
            cf = __expf(mB - mn);
            wg = __expf(e - mn);
            dB = dB * cf + wg;
            aB = aB * cf + wg * hvB;
            mB = mn;
        }
    }
    float bv = bias[tt];
    if (t < 32) {
        out[(size_t)i * 32 + tt] = aA / dA + bv;
        out[(size_t)(i + N_NODES) * 32 + tt] = aB / dB + bv;
    }
}

// ---------------------------------------------------------------------------
extern "C" void kernel_launch(void* const* d_in, const int* in_sizes, int n_in,
                              void* d_out, int out_size, void* d_ws, size_t ws_size,
                              hipStream_t stream) {
    const float* x   = (const float*)d_in[0];
    const float* emb = (const float*)d_in[1];
    const float* Wp  = (const float*)d_in[2];
    const float* bp  = (const float*)d_in[3];
    const float* W1  = (const float*)d_in[4];
    const float* a1s = (const float*)d_in[5];
    const float* a1d = (const float*)d_in[6];
    const float* b1  = (const float*)d_in[7];
    const float* W2  = (const float*)d_in[8];
    const float* a2s = (const float*)d_in[9];
    const float* a2d = (const float*)d_in[10];
    const float* b2  = (const float*)d_in[11];

    const int ROWS = BATCH * N_NODES;  // 8192

    char* w = (char*)d_ws;
    unsigned short* ne_hi = (unsigned short*)w;  w += (size_t)N_NODES * 64 * 2;
    unsigned short* ne_lo = (unsigned short*)w;  w += (size_t)N_NODES * 64 * 2;
    unsigned long long* mask = (unsigned long long*)w; w += (size_t)N_NODES * 64 * 8;
    float* h1  = (float*)w;                      w += (size_t)ROWS * 64 * 4;
    float* s1s = (float*)w;                      w += (size_t)ROWS * 4 * 4;
    float* s1d = (float*)w;                      w += (size_t)ROWS * 4 * 4;
    float* h2  = (float*)w;                      w += (size_t)ROWS * 32 * 4;
    float* s2s = (float*)w;                      w += (size_t)ROWS * 4 * 4;
    float* s2d = (float*)w;                      w += (size_t)ROWS * 4 * 4;

    norm_kernel<<<dim3(256), dim3(256), 0, stream>>>(emb, ne_hi, ne_lo);
    k2_kernel<<<dim3(1280), dim3(256), 0, stream>>>(
        ne_hi, ne_lo, mask, x, Wp, bp, W1, a1s, a1d, h1, s1s, s1d);
    agg1_fused_kernel<<<dim3(N_NODES / 4), dim3(256), 0, stream>>>(
        h1, s1s, s1d, mask, b1, W2, a2s, a2d, h2, s2s, s2d);
    agg2_kernel<<<dim3(N_NODES / 4), dim3(256), 0, stream>>>(
        h2, s2s, s2d, mask, b2, (float*)d_out);
}

// Round 14
// 34.199 us; speedup vs baseline: 1.0604x; 1.0604x over previous
//
#include <hip/hip_runtime.h>
#include <hip/hip_bf16.h>
#include <stdint.h>

#define N_NODES 4096
#define BATCH 2

typedef __attribute__((ext_vector_type(8))) short short8v;
typedef __attribute__((ext_vector_type(4))) unsigned short ushort4v;
typedef __attribute__((ext_vector_type(4))) float f32x4;

#define GLL16(gsrc, ldst) \
    __builtin_amdgcn_global_load_lds((const __attribute__((address_space(1))) void*)(gsrc), \
                                     (__attribute__((address_space(3))) void*)(ldst), 16, 0, 0)

static __device__ inline unsigned short f2bf_rn(float x) {
    unsigned u = __float_as_uint(x);
    unsigned r = (u + 0x7FFFu + ((u >> 16) & 1u)) >> 16;
    return (unsigned short)r;
}
static __device__ inline float bf2f(unsigned short b) {
    return __uint_as_float(((unsigned)b) << 16);
}
static __device__ inline float rl(float v, int k) {   // wave-uniform broadcast
    return __uint_as_float(__builtin_amdgcn_readlane(__float_as_uint(v), k));
}

// ---------------------------------------------------------------------------
// K1: norm only -> split-bf16 ne (adj's sole prerequisite). 16 rows/block.
// ---------------------------------------------------------------------------
__global__ __launch_bounds__(256) void norm_kernel(
        const float* __restrict__ emb,
        unsigned short* __restrict__ ne_hi, unsigned short* __restrict__ ne_lo) {
    int t = threadIdx.x;
    int row = blockIdx.x * 16 + (t >> 4);
    int l16 = t & 15;
    float4 v = *(const float4*)&emb[(size_t)row * 64 + l16 * 4];
    float s = v.x * v.x + v.y * v.y + v.z * v.z + v.w * v.w;
#pragma unroll
    for (int m = 8; m >= 1; m >>= 1) s += __shfl_xor(s, m);
    float inv = 1.f / sqrtf(s);
    float n0 = v.x * inv, n1 = v.y * inv, n2 = v.z * inv, n3 = v.w * inv;
    ushort4v h = {f2bf_rn(n0), f2bf_rn(n1), f2bf_rn(n2), f2bf_rn(n3)};
    ushort4v lo = {f2bf_rn(n0 - bf2f(h.x)), f2bf_rn(n1 - bf2f(h.y)),
                   f2bf_rn(n2 - bf2f(h.z)), f2bf_rn(n3 - bf2f(h.w))};
    *(ushort4v*)&ne_hi[(size_t)row * 64 + l16 * 4] = h;
    *(ushort4v*)&ne_lo[(size_t)row * 64 + l16 * 4] = lo;
}

// ---------------------------------------------------------------------------
// K2 fat kernel: blocks [0,256) feat1; blocks [256,1280) adjacency.
// Adj = R5-verified core: BK=64, 64 KiB LDS, row-major [128][64sh] with
// 8-slot XOR swizzle (conflict-free AND coalesced GLL16 staging), 1 sync.
// ---------------------------------------------------------------------------
__global__ __launch_bounds__(256) void k2_kernel(
        const unsigned short* __restrict__ hi, const unsigned short* __restrict__ lo,
        unsigned long long* __restrict__ mask,
        const float* __restrict__ x, const float* __restrict__ Wp,
        const float* __restrict__ bp, const float* __restrict__ W1,
        const float* __restrict__ a1s, const float* __restrict__ a1d,
        float* __restrict__ h1out, float* __restrict__ ssrc, float* __restrict__ sdst) {
    __shared__ unsigned short Ah[128 * 64];
    __shared__ unsigned short Al[128 * 64];
    __shared__ unsigned short Bh[128 * 64];
    __shared__ unsigned short Bl[128 * 64];
    int t = threadIdx.x;
    int w = t >> 6, l = t & 63;

    if (blockIdx.x < 256) {
        // ================= feat1: proj + mm1 + scores1 (R5-verified) =======
        int b = blockIdx.x;
        int row0 = b * 32 + w * 8;

        float xv[8];
#pragma unroll
        for (int r = 0; r < 8; ++r) xv[r] = x[(size_t)(row0 + r) * 16 + (l & 15)];

        float h0[8];
        float bpv = bp[l];
#pragma unroll
        for (int r = 0; r < 8; ++r) h0[r] = bpv;
#pragma unroll
        for (int k = 0; k < 16; ++k) {
            float wk = Wp[k * 64 + l];
#pragma unroll
            for (int r = 0; r < 8; ++r) h0[r] += rl(xv[r], k) * wk;
        }

        float h1[8] = {0.f, 0.f, 0.f, 0.f, 0.f, 0.f, 0.f, 0.f};
#pragma unroll
        for (int k = 0; k < 64; ++k) {
            float wk = W1[k * 64 + l];
#pragma unroll
            for (int r = 0; r < 8; ++r) h1[r] += rl(h0[r], k) * wk;
        }

        float as_ = a1s[l], ad_ = a1d[l];
#pragma unroll
        for (int r = 0; r < 8; ++r) {
            h1out[(size_t)(row0 + r) * 64 + l] = h1[r];
            float ps = h1[r] * as_, pd = h1[r] * ad_;
#pragma unroll
            for (int m = 8; m >= 1; m >>= 1) {
                ps += __shfl_xor(ps, m);
                pd += __shfl_xor(pd, m);
            }
            if ((l & 15) == 0) {
                ssrc[(size_t)(row0 + r) * 4 + (l >> 4)] = ps;
                sdst[(size_t)(row0 + r) * 4 + (l >> 4)] = pd;
            }
        }
        return;
    }

    // ================= adjacency (R5-verified core) =================
    int tile = blockIdx.x - 256;
    int bi = tile >> 5, bj = tile & 31;
    int i0 = bi * 128, j0 = bj * 128;

    // ---- stage: wave w stages local rows [w*32, w*32+32) of each buffer ----
    int cr = l >> 3;                 // row within 8-row chunk
    int slot = (l & 7) ^ cr;         // pre-swizzled source 16B-slot
#pragma unroll
    for (int q = 0; q < 4; ++q) {
        int lr = w * 32 + q * 8;     // local chunk base row
        size_t ga = (size_t)(i0 + lr + cr) * 64 + slot * 8;
        size_t gb = (size_t)(j0 + lr + cr) * 64 + slot * 8;
        GLL16(hi + ga, &Ah[lr * 64]);
        GLL16(lo + ga, &Al[lr * 64]);
        GLL16(hi + gb, &Bh[lr * 64]);
        GLL16(lo + gb, &Bl[lr * 64]);
    }
    __syncthreads();

    // ---- A fragments for this wave's 2 row-tiles ----
    int fr = l & 15;
    int s0 = l >> 4;                 // k-slot 0..3
    int r7 = l & 7;
    short8v aH[2][2], aL[2][2];
#pragma unroll
    for (int rt = 0; rt < 2; ++rt) {
        int base = (w * 32 + rt * 16 + fr) * 64;
        aH[rt][0] = *(const short8v*)&Ah[base + ((s0 ^ r7) << 3)];
        aH[rt][1] = *(const short8v*)&Ah[base + (((s0 + 4) ^ r7) << 3)];
        aL[rt][0] = *(const short8v*)&Al[base + ((s0 ^ r7) << 3)];
        aL[rt][1] = *(const short8v*)&Al[base + (((s0 + 4) ^ r7) << 3)];
    }

    f32x4 acc[2][8];
#pragma unroll
    for (int rt = 0; rt < 2; ++rt)
#pragma unroll
        for (int js = 0; js < 8; ++js) acc[rt][js] = (f32x4){0.f, 0.f, 0.f, 0.f};

#pragma unroll
    for (int js = 0; js < 8; ++js) {
        int bbase = (js * 16 + fr) * 64;
        short8v bH0 = *(const short8v*)&Bh[bbase + ((s0 ^ r7) << 3)];
        short8v bH1 = *(const short8v*)&Bh[bbase + (((s0 + 4) ^ r7) << 3)];
        short8v bL0 = *(const short8v*)&Bl[bbase + ((s0 ^ r7) << 3)];
        short8v bL1 = *(const short8v*)&Bl[bbase + (((s0 + 4) ^ r7) << 3)];
#pragma unroll
        for (int rt = 0; rt < 2; ++rt) {
            f32x4 a = acc[rt][js];
            a = __builtin_amdgcn_mfma_f32_16x16x32_bf16(aH[rt][0], bH0, a, 0, 0, 0);
            a = __builtin_amdgcn_mfma_f32_16x16x32_bf16(aH[rt][1], bH1, a, 0, 0, 0);
            a = __builtin_amdgcn_mfma_f32_16x16x32_bf16(aH[rt][0], bL0, a, 0, 0, 0);
            a = __builtin_amdgcn_mfma_f32_16x16x32_bf16(aH[rt][1], bL1, a, 0, 0, 0);
            a = __builtin_amdgcn_mfma_f32_16x16x32_bf16(aL[rt][0], bH0, a, 0, 0, 0);
            a = __builtin_amdgcn_mfma_f32_16x16x32_bf16(aL[rt][1], bH1, a, 0, 0, 0);
            acc[rt][js] = a;
        }
    }

    // ---- pack to bitmask. C/D layout: col=lane&15, row=(lane>>4)*4+reg ----
    int shift = ((l & 15) >> 2) * 16;
    int r = l & 3;
#pragma unroll
    for (int rt = 0; rt < 2; ++rt) {
#pragma unroll
        for (int ws_ = 0; ws_ < 2; ++ws_) {
            unsigned long long w64 = 0;
#pragma unroll
            for (int js2 = 0; js2 < 4; ++js2) {
                f32x4 a = acc[rt][ws_ * 4 + js2];
                unsigned long long c0 = __ballot(a[0] > 0.5f);
                unsigned long long c1 = __ballot(a[1] > 0.5f);
                unsigned long long c2 = __ballot(a[2] > 0.5f);
                unsigned long long c3 = __ballot(a[3] > 0.5f);
                unsigned long long sel = r == 0 ? c0 : r == 1 ? c1 : r == 2 ? c2 : c3;
                w64 |= ((sel >> shift) & 0xFFFFULL) << (js2 * 16);
            }
            if (l < 16)
                mask[(size_t)(i0 + w * 32 + rt * 16 + l) * 64 + bj * 2 + ws_] = w64;
        }
    }
}

// ---------------------------------------------------------------------------
// K3 (R11-verified): agg1(+bias+ReLU)+mm2+scores2, batch-paired.
// ---------------------------------------------------------------------------
__global__ __launch_bounds__(256) void agg1_fused_kernel(
        const float* __restrict__ h1, const float* __restrict__ ssrc,
        const float* __restrict__ sdst, const unsigned long long* __restrict__ mask,
        const float* __restrict__ b1, const float* __restrict__ W2,
        const float* __restrict__ a2s, const float* __restrict__ a2d,
        float* __restrict__ h2out, float* __restrict__ s2s, float* __restrict__ s2d) {
    int i = blockIdx.x * 4 + (threadIdx.x >> 6);   // node 0..4095
    int t = threadIdx.x & 63;
    int hh = t >> 4;

    float sdA = sdst[(size_t)i * 4 + hh];
    float sdB = sdst[(size_t)(i + N_NODES) * 4 + hh];
    unsigned long long myword = mask[(size_t)i * 64 + t];

    float mA = -1e30f, dA = 0.f, aA = 0.f;
    float mB = -1e30f, dB = 0.f, aB = 0.f;
    unsigned long long nz = __ballot(myword != 0ULL);
    while (nz) {
        int lw = __ffsll(nz) - 1;
        nz &= nz - 1;
        unsigned long long wbits = __shfl(myword, lw);
        while (wbits) {
            int bpos = __ffsll(wbits) - 1;
            wbits &= wbits - 1;
            int j = (lw << 6) + bpos;
            float ssA = ssrc[(size_t)j * 4 + hh];
            float ssB = ssrc[(size_t)(j + N_NODES) * 4 + hh];
            float hvA = h1[(size_t)j * 64 + t];
            float hvB = h1[(size_t)(j + N_NODES) * 64 + t];
            float e = sdA + ssA;
            e = e > 0.f ? e : 0.2f * e;
            float mn = fmaxf(mA, e);
            float cf = __expf(mA - mn);
            float wg = __expf(e - mn);
            dA = dA * cf + wg;
            aA = aA * cf + wg * hvA;
            mA = mn;
            e = sdB + ssB;
            e = e > 0.f ? e : 0.2f * e;
            mn = fmaxf(mB, e);
            cf = __expf(mB - mn);
            wg = __expf(e - mn);
            dB = dB * cf + wg;
            aB = aB * cf + wg * hvB;
            mB = mn;
        }
    }
    float b1v = b1[t];
    float oA = fmaxf(aA / dA + b1v, 0.f);
    float oB = fmaxf(aB / dB + b1v, 0.f);

    // mm2 for both rows (lanes 32..63 duplicate 0..31)
    int l2 = t & 31;
    float acc2A = 0.f, acc2B = 0.f;
#pragma unroll
    for (int k = 0; k < 64; ++k) {
        float wk = W2[k * 32 + l2];
        acc2A += rl(oA, k) * wk;
        acc2B += rl(oB, k) * wk;
    }

    float a2sv = a2s[l2], a2dv = a2d[l2];
    float psA = acc2A * a2sv, pdA = acc2A * a2dv;
    float psB = acc2B * a2sv, pdB = acc2B * a2dv;
#pragma unroll
    for (int mm = 4; mm >= 1; mm >>= 1) {
        psA += __shfl_xor(psA, mm);
        pdA += __shfl_xor(pdA, mm);
        psB += __shfl_xor(psB, mm);
        pdB += __shfl_xor(pdB, mm);
    }
    if (t < 32) {
        h2out[(size_t)i * 32 + t] = acc2A;
        h2out[(size_t)(i + N_NODES) * 32 + t] = acc2B;
        if ((t & 7) == 0) {
            s2s[(size_t)i * 4 + (t >> 3)] = psA;
            s2d[(size_t)i * 4 + (t >> 3)] = pdA;
            s2s[(size_t)(i + N_NODES) * 4 + (t >> 3)] = psB;
            s2d[(size_t)(i + N_NODES) * 4 + (t >> 3)] = pdB;
        }
    }
}

// ---------------------------------------------------------------------------
// K4 (R11-verified): agg2, batch-paired -> d_out.
// ---------------------------------------------------------------------------
__global__ __launch_bounds__(256) void agg2_kernel(
        const float* __restrict__ hfeat, const float* __restrict__ ssrc,
        const float* __restrict__ sdst, const unsigned long long* __restrict__ mask,
        const float* __restrict__ bias, float* __restrict__ out) {
    int i = blockIdx.x * 4 + (threadIdx.x >> 6);   // node 0..4095
    int t = threadIdx.x & 63;
    int tt = t & 31;
    int hh = tt >> 3;

    float sdA = sdst[(size_t)i * 4 + hh];
    float sdB = sdst[(size_t)(i + N_NODES) * 4 + hh];
    unsigned long long myword = mask[(size_t)i * 64 + t];

    float mA = -1e30f, dA = 0.f, aA = 0.f;
    float mB = -1e30f, dB = 0.f, aB = 0.f;
    unsigned long long nz = __ballot(myword != 0ULL);
    while (nz) {
        int lw = __ffsll(nz) - 1;
        nz &= nz - 1;
        unsigned long long wbits = __shfl(myword, lw);
        while (wbits) {
            int bpos = __ffsll(wbits) - 1;
            wbits &= wbits - 1;
            int j = (lw << 6) + bpos;
            float ssA = ssrc[(size_t)j * 4 + hh];
            float ssB = ssrc[(size_t)(j + N_NODES) * 4 + hh];
            float hvA = hfeat[(size_t)j * 32 + tt];
            float hvB = hfeat[(size_t)(j + N_NODES) * 32 + tt];
            float e = sdA + ssA;
            e = e > 0.f ? e : 0.2f * e;
            float mn = fmaxf(mA, e);
            float cf = __expf(mA - mn);
            float wg = __expf(e - mn);
            dA = dA * cf + wg;
            aA = aA * cf + wg * hvA;
            mA = mn;
            e = sdB + ssB;
            e = e > 0.f ? e : 0.2f * e;
            mn = fmaxf(mB, e);
            cf = __expf(mB - mn);
            wg = __expf(e - mn);
            dB = dB * cf + wg;
            aB = aB * cf + wg * hvB;
            mB = mn;
        }
    }
    float bv = bias[tt];
    if (t < 32) {
        out[(size_t)i * 32 + tt] = aA / dA + bv;
        out[(size_t)(i + N_NODES) * 32 + tt] = aB / dB + bv;
    }
}

// ---------------------------------------------------------------------------
extern "C" void kernel_launch(void* const* d_in, const int* in_sizes, int n_in,
                              void* d_out, int out_size, void* d_ws, size_t ws_size,
                              hipStream_t stream) {
    const float* x   = (const float*)d_in[0];
    const float* emb = (const float*)d_in[1];
    const float* Wp  = (const float*)d_in[2];
    const float* bp  = (const float*)d_in[3];
    const float* W1  = (const float*)d_in[4];
    const float* a1s = (const float*)d_in[5];
    const float* a1d = (const float*)d_in[6];
    const float* b1  = (const float*)d_in[7];
    const float* W2  = (const float*)d_in[8];
    const float* a2s = (const float*)d_in[9];
    const float* a2d = (const float*)d_in[10];
    const float* b2  = (const float*)d_in[11];

    const int ROWS = BATCH * N_NODES;  // 8192

    char* w = (char*)d_ws;
    unsigned short* ne_hi = (unsigned short*)w;  w += (size_t)N_NODES * 64 * 2;
    unsigned short* ne_lo = (unsigned short*)w;  w += (size_t)N_NODES * 64 * 2;
    unsigned long long* mask = (unsigned long long*)w; w += (size_t)N_NODES * 64 * 8;
    float* h1  = (float*)w;                      w += (size_t)ROWS * 64 * 4;
    float* s1s = (float*)w;                      w += (size_t)ROWS * 4 * 4;
    float* s1d = (float*)w;                      w += (size_t)ROWS * 4 * 4;
    float* h2  = (float*)w;                      w += (size_t)ROWS * 32 * 4;
    float* s2s = (float*)w;                      w += (size_t)ROWS * 4 * 4;
    float* s2d = (float*)w;                      w += (size_t)ROWS * 4 * 4;

    norm_kernel<<<dim3(256), dim3(256), 0, stream>>>(emb, ne_hi, ne_lo);
    k2_kernel<<<dim3(1280), dim3(256), 0, stream>>>(
        ne_hi, ne_lo, mask, x, Wp, bp, W1, a1s, a1d, h1, s1s, s1d);
    agg1_fused_kernel<<<dim3(N_NODES / 4), dim3(256), 0, stream>>>(
        h1, s1s, s1d, mask, b1, W2, a2s, a2d, h2, s2s, s2d);
    agg2_kernel<<<dim3(N_NODES / 4), dim3(256), 0, stream>>>(
        h2, s2s, s2d, mask, b2, (float*)d_out);
}

// Round 15
// 33.694 us; speedup vs baseline: 1.0763x; 1.0150x over previous
//
#include <hip/hip_runtime.h>
#include <hip/hip_bf16.h>
#include <stdint.h>

#define N_NODES 4096
#define BATCH 2

typedef __attribute__((ext_vector_type(8))) short short8v;
typedef __attribute__((ext_vector_type(4))) float f32x4;

static __device__ inline float bf2f(unsigned short b) {
    return __uint_as_float(((unsigned)b) << 16);
}
static __device__ inline float rl(float v, int k) {   // wave-uniform broadcast
    return __uint_as_float(__builtin_amdgcn_readlane(__float_as_uint(v), k));
}

// Split 2 floats into bf16 hi (RNE) + bf16 lo (residual), packed as u32s.
static __device__ inline void cvt2(float f0, float f1, unsigned* hi, unsigned* lo) {
    float2 p;
    p.x = f0;
    p.y = f1;
    __hip_bfloat162 h = __float22bfloat162_rn(p);
    unsigned hb;
    __builtin_memcpy(&hb, &h, 4);
    p.x = f0 - bf2f((unsigned short)hb);
    p.y = f1 - bf2f((unsigned short)(hb >> 16));
    __hip_bfloat162 l2v = __float22bfloat162_rn(p);
    unsigned lb;
    __builtin_memcpy(&lb, &l2v, 4);
    *hi = hb;
    *lo = lb;
}

// ---------------------------------------------------------------------------
// K2 fat kernel: blocks [0,256) feat1; blocks [256,1280) adjacency.
// Adj is SELF-CONTAINED: stages raw fp32 emb -> in-register bf16 hi/lo split
// -> R5-verified swizzled LDS layout; row norms computed during staging;
// threshold scaled per (row,col): dot_raw > 0.5 * n_i * n_j.
// ---------------------------------------------------------------------------
__global__ __launch_bounds__(256) void k2_kernel(
        const float* __restrict__ emb, unsigned long long* __restrict__ mask,
        const float* __restrict__ x, const float* __restrict__ Wp,
        const float* __restrict__ bp, const float* __restrict__ W1,
        const float* __restrict__ a1s, const float* __restrict__ a1d,
        float* __restrict__ h1out, float* __restrict__ ssrc, float* __restrict__ sdst) {
    __shared__ unsigned short Ah[128 * 64];
    __shared__ unsigned short Al[128 * 64];
    __shared__ unsigned short Bh[128 * 64];
    __shared__ unsigned short Bl[128 * 64];
    __shared__ float An[128];
    __shared__ float Bn[128];
    int t = threadIdx.x;
    int w = t >> 6, l = t & 63;

    if (blockIdx.x < 256) {
        // ================= feat1: proj + mm1 + scores1 (R5-verified) =======
        int b = blockIdx.x;
        int row0 = b * 32 + w * 8;

        float xv[8];
#pragma unroll
        for (int r = 0; r < 8; ++r) xv[r] = x[(size_t)(row0 + r) * 16 + (l & 15)];

        float h0[8];
        float bpv = bp[l];
#pragma unroll
        for (int r = 0; r < 8; ++r) h0[r] = bpv;
#pragma unroll
        for (int k = 0; k < 16; ++k) {
            float wk = Wp[k * 64 + l];
#pragma unroll
            for (int r = 0; r < 8; ++r) h0[r] += rl(xv[r], k) * wk;
        }

        float h1[8] = {0.f, 0.f, 0.f, 0.f, 0.f, 0.f, 0.f, 0.f};
#pragma unroll
        for (int k = 0; k < 64; ++k) {
            float wk = W1[k * 64 + l];
#pragma unroll
            for (int r = 0; r < 8; ++r) h1[r] += rl(h0[r], k) * wk;
        }

        float as_ = a1s[l], ad_ = a1d[l];
#pragma unroll
        for (int r = 0; r < 8; ++r) {
            h1out[(size_t)(row0 + r) * 64 + l] = h1[r];
            float ps = h1[r] * as_, pd = h1[r] * ad_;
#pragma unroll
            for (int m = 8; m >= 1; m >>= 1) {
                ps += __shfl_xor(ps, m);
                pd += __shfl_xor(pd, m);
            }
            if ((l & 15) == 0) {
                ssrc[(size_t)(row0 + r) * 4 + (l >> 4)] = ps;
                sdst[(size_t)(row0 + r) * 4 + (l >> 4)] = pd;
            }
        }
        return;
    }

    // ================= adjacency (self-contained) =================
    int tile = blockIdx.x - 256;
    int bi = tile >> 5, bj = tile & 31;
    int i0 = bi * 128, j0 = bj * 128;

    // ---- stage: wave w handles rows [w*32, w*32+32); lane pair (2k,2k+1)
    //      covers row k's two halves (slots 0-3 / 4-7). Raw fp32 load ->
    //      bf16 split in regs -> swizzled ds_write (R5 layout). Norms too.
    {
        int rhalf = l >> 1, half = l & 1;
        int row = w * 32 + rhalf;            // local row 0..127
        float na = 0.f, nb = 0.f;
#pragma unroll
        for (int q = 0; q < 4; ++q) {
            int slot = half * 4 + q;         // 16B slot 0..7 (8 elems)
            const float* pa = &emb[(size_t)(i0 + row) * 64 + slot * 8];
            const float* pb = &emb[(size_t)(j0 + row) * 64 + slot * 8];
            float4 a0 = *(const float4*)pa;
            float4 a1 = *(const float4*)(pa + 4);
            float4 b0 = *(const float4*)pb;
            float4 b1 = *(const float4*)(pb + 4);
            na += a0.x * a0.x + a0.y * a0.y + a0.z * a0.z + a0.w * a0.w +
                  a1.x * a1.x + a1.y * a1.y + a1.z * a1.z + a1.w * a1.w;
            nb += b0.x * b0.x + b0.y * b0.y + b0.z * b0.z + b0.w * b0.w +
                  b1.x * b1.x + b1.y * b1.y + b1.z * b1.z + b1.w * b1.w;

            union {
                unsigned u[4];
                short8v v;
            } HA, LA, HB, LB;
            cvt2(a0.x, a0.y, &HA.u[0], &LA.u[0]);
            cvt2(a0.z, a0.w, &HA.u[1], &LA.u[1]);
            cvt2(a1.x, a1.y, &HA.u[2], &LA.u[2]);
            cvt2(a1.z, a1.w, &HA.u[3], &LA.u[3]);
            cvt2(b0.x, b0.y, &HB.u[0], &LB.u[0]);
            cvt2(b0.z, b0.w, &HB.u[1], &LB.u[1]);
            cvt2(b1.x, b1.y, &HB.u[2], &LB.u[2]);
            cvt2(b1.z, b1.w, &HB.u[3], &LB.u[3]);

            int ss = ((slot ^ (row & 7)) << 3);
            *(short8v*)&Ah[row * 64 + ss] = HA.v;
            *(short8v*)&Al[row * 64 + ss] = LA.v;
            *(short8v*)&Bh[row * 64 + ss] = HB.v;
            *(short8v*)&Bl[row * 64 + ss] = LB.v;
        }
        na += __shfl_xor(na, 1);
        nb += __shfl_xor(nb, 1);
        if (half == 0) {
            An[row] = sqrtf(na);
            Bn[row] = sqrtf(nb);
        }
    }
    __syncthreads();

    // ---- A fragments for this wave's 2 row-tiles (R5-verified reader) ----
    int fr = l & 15;
    int s0 = l >> 4;                 // k-slot 0..3
    int r7 = l & 7;
    short8v aH[2][2], aL[2][2];
#pragma unroll
    for (int rt = 0; rt < 2; ++rt) {
        int base = (w * 32 + rt * 16 + fr) * 64;
        aH[rt][0] = *(const short8v*)&Ah[base + ((s0 ^ r7) << 3)];
        aH[rt][1] = *(const short8v*)&Ah[base + (((s0 + 4) ^ r7) << 3)];
        aL[rt][0] = *(const short8v*)&Al[base + ((s0 ^ r7) << 3)];
        aL[rt][1] = *(const short8v*)&Al[base + (((s0 + 4) ^ r7) << 3)];
    }

    f32x4 acc[2][8];
#pragma unroll
    for (int rt = 0; rt < 2; ++rt)
#pragma unroll
        for (int js = 0; js < 8; ++js) acc[rt][js] = (f32x4){0.f, 0.f, 0.f, 0.f};

#pragma unroll
    for (int js = 0; js < 8; ++js) {
        int bbase = (js * 16 + fr) * 64;
        short8v bH0 = *(const short8v*)&Bh[bbase + ((s0 ^ r7) << 3)];
        short8v bH1 = *(const short8v*)&Bh[bbase + (((s0 + 4) ^ r7) << 3)];
        short8v bL0 = *(const short8v*)&Bl[bbase + ((s0 ^ r7) << 3)];
        short8v bL1 = *(const short8v*)&Bl[bbase + (((s0 + 4) ^ r7) << 3)];
#pragma unroll
        for (int rt = 0; rt < 2; ++rt) {
            f32x4 a = acc[rt][js];
            a = __builtin_amdgcn_mfma_f32_16x16x32_bf16(aH[rt][0], bH0, a, 0, 0, 0);
            a = __builtin_amdgcn_mfma_f32_16x16x32_bf16(aH[rt][1], bH1, a, 0, 0, 0);
            a = __builtin_amdgcn_mfma_f32_16x16x32_bf16(aH[rt][0], bL0, a, 0, 0, 0);
            a = __builtin_amdgcn_mfma_f32_16x16x32_bf16(aH[rt][1], bL1, a, 0, 0, 0);
            a = __builtin_amdgcn_mfma_f32_16x16x32_bf16(aL[rt][0], bH0, a, 0, 0, 0);
            a = __builtin_amdgcn_mfma_f32_16x16x32_bf16(aL[rt][1], bH1, a, 0, 0, 0);
            acc[rt][js] = a;
        }
    }

    // ---- pack to bitmask with scaled threshold 0.5*n_i*n_j.
    //      C/D layout: col=lane&15, row=(lane>>4)*4+reg.
    int shift = ((l & 15) >> 2) * 16;
    int r = l & 3;
#pragma unroll
    for (int rt = 0; rt < 2; ++rt) {
        int rb = w * 32 + rt * 16 + (l >> 4) * 4;
        float n0 = 0.5f * An[rb + 0];
        float n1 = 0.5f * An[rb + 1];
        float n2 = 0.5f * An[rb + 2];
        float n3 = 0.5f * An[rb + 3];
#pragma unroll
        for (int ws_ = 0; ws_ < 2; ++ws_) {
            unsigned long long w64 = 0;
#pragma unroll
            for (int js2 = 0; js2 < 4; ++js2) {
                int js = ws_ * 4 + js2;
                float nbv = Bn[js * 16 + (l & 15)];
                f32x4 a = acc[rt][js];
                unsigned long long c0 = __ballot(a[0] > n0 * nbv);
                unsigned long long c1 = __ballot(a[1] > n1 * nbv);
                unsigned long long c2 = __ballot(a[2] > n2 * nbv);
                unsigned long long c3 = __ballot(a[3] > n3 * nbv);
                unsigned long long sel = r == 0 ? c0 : r == 1 ? c1 : r == 2 ? c2 : c3;
                w64 |= ((sel >> shift) & 0xFFFFULL) << (js2 * 16);
            }
            if (l < 16)
                mask[(size_t)(i0 + w * 32 + rt * 16 + l) * 64 + bj * 2 + ws_] = w64;
        }
    }
}

// ---------------------------------------------------------------------------
// K3 (R11-verified): agg1(+bias+ReLU)+mm2+scores2, batch-paired.
// ---------------------------------------------------------------------------
__global__ __launch_bounds__(256) void agg1_fused_kernel(
        const float* __restrict__ h1, const float* __restrict__ ssrc,
        const float* __restrict__ sdst, const unsigned long long* __restrict__ mask,
        const float* __restrict__ b1, const float* __restrict__ W2,
        const float* __restrict__ a2s, const float* __restrict__ a2d,
        float* __restrict__ h2out, float* __restrict__ s2s, float* __restrict__ s2d) {
    int i = blockIdx.x * 4 + (threadIdx.x >> 6);   // node 0..4095
    int t = threadIdx.x & 63;
    int hh = t >> 4;

    float sdA = sdst[(size_t)i * 4 + hh];
    float sdB = sdst[(size_t)(i + N_NODES) * 4 + hh];
    unsigned long long myword = mask[(size_t)i * 64 + t];

    float mA = -1e30f, dA = 0.f, aA = 0.f;
    float mB = -1e30f, dB = 0.f, aB = 0.f;
    unsigned long long nz = __ballot(myword != 0ULL);
    while (nz) {
        int lw = __ffsll(nz) - 1;
        nz &= nz - 1;
        unsigned long long wbits = __shfl(myword, lw);
        while (wbits) {
            int bpos = __ffsll(wbits) - 1;
            wbits &= wbits - 1;
            int j = (lw << 6) + bpos;
            float ssA = ssrc[(size_t)j * 4 + hh];
            float ssB = ssrc[(size_t)(j + N_NODES) * 4 + hh];
            float hvA = h1[(size_t)j * 64 + t];
            float hvB = h1[(size_t)(j + N_NODES) * 64 + t];
            float e = sdA + ssA;
            e = e > 0.f ? e : 0.2f * e;
            float mn = fmaxf(mA, e);
            float cf = __expf(mA - mn);
            float wg = __expf(e - mn);
            dA = dA * cf + wg;
            aA = aA * cf + wg * hvA;
            mA = mn;
            e = sdB + ssB;
            e = e > 0.f ? e : 0.2f * e;
            mn = fmaxf(mB, e);
            cf = __expf(mB - mn);
            wg = __expf(e - mn);
            dB = dB * cf + wg;
            aB = aB * cf + wg * hvB;
            mB = mn;
        }
    }
    float b1v = b1[t];
    float oA = fmaxf(aA / dA + b1v, 0.f);
    float oB = fmaxf(aB / dB + b1v, 0.f);

    // mm2 for both rows (lanes 32..63 duplicate 0..31)
    int l2 = t & 31;
    float acc2A = 0.f, acc2B = 0.f;
#pragma unroll
    for (int k = 0; k < 64; ++k) {
        float wk = W2[k * 32 + l2];
        acc2A += rl(oA, k) * wk;
        acc2B += rl(oB, k) * wk;
    }

    float a2sv = a2s[l2], a2dv = a2d[l2];
    float psA = acc2A * a2sv, pdA = acc2A * a2dv;
    float psB = acc2B * a2sv, pdB = acc2B * a2dv;
#pragma unroll
    for (int mm = 4; mm >= 1; mm >>= 1) {
        psA += __shfl_xor(psA, mm);
        pdA += __shfl_xor(pdA, mm);
        psB += __shfl_xor(psB, mm);
        pdB += __shfl_xor(pdB, mm);
    }
    if (t < 32) {
        h2out[(size_t)i * 32 + t] = acc2A;
        h2out[(size_t)(i + N_NODES) * 32 + t] = acc2B;
        if ((t & 7) == 0) {
            s2s[(size_t)i * 4 + (t >> 3)] = psA;
            s2d[(size_t)i * 4 + (t >> 3)] = pdA;
            s2s[(size_t)(i + N_NODES) * 4 + (t >> 3)] = psB;
            s2d[(size_t)(i + N_NODES) * 4 + (t >> 3)] = pdB;
        }
    }
}

// ---------------------------------------------------------------------------
// K4 (R11-verified): agg2, batch-paired -> d_out.
// ---------------------------------------------------------------------------
__global__ __launch_bounds__(256) void agg2_kernel(
        const float* __restrict__ hfeat, const float* __restrict__ ssrc,
        const float* __restrict__ sdst, const unsigned long long* __restrict__ mask,
        const float* __restrict__ bias, float* __restrict__ out) {
    int i = blockIdx.x * 4 + (threadIdx.x >> 6);   // node 0..4095
    int t = threadIdx.x & 63;
    int tt = t & 31;
    int hh = tt >> 3;

    float sdA = sdst[(size_t)i * 4 + hh];
    float sdB = sdst[(size_t)(i + N_NODES) * 4 + hh];
    unsigned long long myword = mask[(size_t)i * 64 + t];

    float mA = -1e30f, dA = 0.f, aA = 0.f;
    float mB = -1e30f, dB = 0.f, aB = 0.f;
    unsigned long long nz = __ballot(myword != 0ULL);
    while (nz) {
        int lw = __ffsll(nz) - 1;
        nz &= nz - 1;
        unsigned long long wbits = __shfl(myword, lw);
        while (wbits) {
            int bpos = __ffsll(wbits) - 1;
            wbits &= wbits - 1;
            int j = (lw << 6) + bpos;
            float ssA = ssrc[(size_t)j * 4 + hh];
            float ssB = ssrc[(size_t)(j + N_NODES) * 4 + hh];
            float hvA = hfeat[(size_t)j * 32 + tt];
            float hvB = hfeat[(size_t)(j + N_NODES) * 32 + tt];
            float e = sdA + ssA;
            e = e > 0.f ? e : 0.2f * e;
            float mn = fmaxf(mA, e);
            float cf = __expf(mA - mn);
            float wg = __expf(e - mn);
            dA = dA * cf + wg;
            aA = aA * cf + wg * hvA;
            mA = mn;
            e = sdB + ssB;
            e = e > 0.f ? e : 0.2f * e;
            mn = fmaxf(mB, e);
            cf = __expf(mB - mn);
            wg = __expf(e - mn);
            dB = dB * cf + wg;
            aB = aB * cf + wg * hvB;
            mB = mn;
        }
    }
    float bv = bias[tt];
    if (t < 32) {
        out[(size_t)i * 32 + tt] = aA / dA + bv;
        out[(size_t)(i + N_NODES) * 32 + tt] = aB / dB + bv;
    }
}

// ---------------------------------------------------------------------------
extern "C" void kernel_launch(void* const* d_in, const int* in_sizes, int n_in,
                              void* d_out, int out_size, void* d_ws, size_t ws_size,
                              hipStream_t stream) {
    const float* x   = (const float*)d_in[0];
    const float* emb = (const float*)d_in[1];
    const float* Wp  = (const float*)d_in[2];
    const float* bp  = (const float*)d_in[3];
    const float* W1  = (const float*)d_in[4];
    const float* a1s = (const float*)d_in[5];
    const float* a1d = (const float*)d_in[6];
    const float* b1  = (const float*)d_in[7];
    const float* W2  = (const float*)d_in[8];
    const float* a2s = (const float*)d_in[9];
    const float* a2d = (const float*)d_in[10];
    const float* b2  = (const float*)d_in[11];

    const int ROWS = BATCH * N_NODES;  // 8192

    char* w = (char*)d_ws;
    unsigned long long* mask = (unsigned long long*)w; w += (size_t)N_NODES * 64 * 8;
    float* h1  = (float*)w;                      w += (size_t)ROWS * 64 * 4;
    float* s1s = (float*)w;                      w += (size_t)ROWS * 4 * 4;
    float* s1d = (float*)w;                      w += (size_t)ROWS * 4 * 4;
    float* h2  = (float*)w;                      w += (size_t)ROWS * 32 * 4;
    float* s2s = (float*)w;                      w += (size_t)ROWS * 4 * 4;
    float* s2d = (float*)w;                      w += (size_t)ROWS * 4 * 4;

    k2_kernel<<<dim3(1280), dim3(256), 0, stream>>>(
        emb, mask, x, Wp, bp, W1, a1s, a1d, h1, s1s, s1d);
    agg1_fused_kernel<<<dim3(N_NODES / 4), dim3(256), 0, stream>>>(
        h1, s1s, s1d, mask, b1, W2, a2s, a2d, h2, s2s, s2d);
    agg2_kernel<<<dim3(N_NODES / 4), dim3(256), 0, stream>>>(
        h2, s2s, s2d, mask, b2, (float*)d_out);
}

// Round 16
// 33.095 us; speedup vs baseline: 1.0958x; 1.0181x over previous
//
#include <hip/hip_runtime.h>
#include <hip/hip_bf16.h>
#include <stdint.h>

#define N_NODES 4096
#define BATCH 2

typedef __attribute__((ext_vector_type(8))) short short8v;
typedef __attribute__((ext_vector_type(4))) float f32x4;

static __device__ inline float bf2f(unsigned short b) {
    return __uint_as_float(((unsigned)b) << 16);
}
static __device__ inline float rl(float v, int k) {   // wave-uniform broadcast
    return __uint_as_float(__builtin_amdgcn_readlane(__float_as_uint(v), k));
}

// Split 2 floats into bf16 hi (RNE) + bf16 lo (residual), packed as u32s.
static __device__ inline void cvt2(float f0, float f1, unsigned* hi, unsigned* lo) {
    float2 p;
    p.x = f0;
    p.y = f1;
    __hip_bfloat162 h = __float22bfloat162_rn(p);
    unsigned hb;
    __builtin_memcpy(&hb, &h, 4);
    p.x = f0 - bf2f((unsigned short)hb);
    p.y = f1 - bf2f((unsigned short)(hb >> 16));
    __hip_bfloat162 l2v = __float22bfloat162_rn(p);
    unsigned lb;
    __builtin_memcpy(&lb, &l2v, 4);
    *hi = hb;
    *lo = lb;
}

// Stage one 128-row fp32 panel -> split-bf16 swizzled LDS + row norms.
// Lane pair (2k,2k+1) covers row k's two slot-halves. (R15-verified layout.)
static __device__ inline void stage_one(const float* __restrict__ emb, int g0,
                                        unsigned short* H, unsigned short* L,
                                        float* Nrm, int w, int l) {
    int rhalf = l >> 1, half = l & 1;
    int row = w * 32 + rhalf;            // local row 0..127
    float n = 0.f;
#pragma unroll
    for (int q = 0; q < 4; ++q) {
        int slot = half * 4 + q;         // 16B slot 0..7 (8 elems)
        const float* pa = &emb[(size_t)(g0 + row) * 64 + slot * 8];
        float4 a0 = *(const float4*)pa;
        float4 a1 = *(const float4*)(pa + 4);
        n += a0.x * a0.x + a0.y * a0.y + a0.z * a0.z + a0.w * a0.w +
             a1.x * a1.x + a1.y * a1.y + a1.z * a1.z + a1.w * a1.w;
        union {
            unsigned u[4];
            short8v v;
        } HH, LL;
        cvt2(a0.x, a0.y, &HH.u[0], &LL.u[0]);
        cvt2(a0.z, a0.w, &HH.u[1], &LL.u[1]);
        cvt2(a1.x, a1.y, &HH.u[2], &LL.u[2]);
        cvt2(a1.z, a1.w, &HH.u[3], &LL.u[3]);
        int ss = ((slot ^ (row & 7)) << 3);
        *(short8v*)&H[row * 64 + ss] = HH.v;
        *(short8v*)&L[row * 64 + ss] = LL.v;
    }
    n += __shfl_xor(n, 1);
    if (half == 0) Nrm[row] = sqrtf(n);
}

// ---------------------------------------------------------------------------
// K2 fat kernel: blocks [0,256) feat1; blocks [256,512) adjacency 4-TILE:
// one j-panel (B staged once) x 4 i-panels. Grid = 512 = one full round.
// Threshold scaled per (row,col): dot_raw > 0.5 * n_i * n_j.
// ---------------------------------------------------------------------------
__global__ __launch_bounds__(256) void k2_kernel(
        const float* __restrict__ emb, unsigned long long* __restrict__ mask,
        const float* __restrict__ x, const float* __restrict__ Wp,
        const float* __restrict__ bp, const float* __restrict__ W1,
        const float* __restrict__ a1s, const float* __restrict__ a1d,
        float* __restrict__ h1out, float* __restrict__ ssrc, float* __restrict__ sdst) {
    __shared__ unsigned short Ah[128 * 64];
    __shared__ unsigned short Al[128 * 64];
    __shared__ unsigned short Bh[128 * 64];
    __shared__ unsigned short Bl[128 * 64];
    __shared__ float An[128];
    __shared__ float Bn[128];
    int t = threadIdx.x;
    int w = t >> 6, l = t & 63;

    if (blockIdx.x < 256) {
        // ================= feat1: proj + mm1 + scores1 (R5-verified) =======
        int b = blockIdx.x;
        int row0 = b * 32 + w * 8;

        float xv[8];
#pragma unroll
        for (int r = 0; r < 8; ++r) xv[r] = x[(size_t)(row0 + r) * 16 + (l & 15)];

        float h0[8];
        float bpv = bp[l];
#pragma unroll
        for (int r = 0; r < 8; ++r) h0[r] = bpv;
#pragma unroll
        for (int k = 0; k < 16; ++k) {
            float wk = Wp[k * 64 + l];
#pragma unroll
            for (int r = 0; r < 8; ++r) h0[r] += rl(xv[r], k) * wk;
        }

        float h1[8] = {0.f, 0.f, 0.f, 0.f, 0.f, 0.f, 0.f, 0.f};
#pragma unroll
        for (int k = 0; k < 64; ++k) {
            float wk = W1[k * 64 + l];
#pragma unroll
            for (int r = 0; r < 8; ++r) h1[r] += rl(h0[r], k) * wk;
        }

        float as_ = a1s[l], ad_ = a1d[l];
#pragma unroll
        for (int r = 0; r < 8; ++r) {
            h1out[(size_t)(row0 + r) * 64 + l] = h1[r];
            float ps = h1[r] * as_, pd = h1[r] * ad_;
#pragma unroll
            for (int m = 8; m >= 1; m >>= 1) {
                ps += __shfl_xor(ps, m);
                pd += __shfl_xor(pd, m);
            }
            if ((l & 15) == 0) {
                ssrc[(size_t)(row0 + r) * 4 + (l >> 4)] = ps;
                sdst[(size_t)(row0 + r) * 4 + (l >> 4)] = pd;
            }
        }
        return;
    }

    // ================= adjacency: 4 i-panels x 1 j-panel =================
    int tile4 = blockIdx.x - 256;        // 0..255
    int bi4 = tile4 >> 5;                // 0..7
    int bj = tile4 & 31;
    int j0 = bj * 128;

    stage_one(emb, j0, Bh, Bl, Bn, w, l);   // B staged ONCE

    int fr = l & 15;
    int s0 = l >> 4;                     // k-slot 0..3
    int r7 = l & 7;
    int shift = ((l & 15) >> 2) * 16;
    int r = l & 3;

#pragma unroll 1
    for (int p = 0; p < 4; ++p) {
        int i0 = (bi4 * 4 + p) * 128;
        stage_one(emb, i0, Ah, Al, An, w, l);
        __syncthreads();                 // A(p)+(& B on p=0) visible

        // ---- A fragments (R5-verified reader) ----
        short8v aH[2][2], aL[2][2];
#pragma unroll
        for (int rt = 0; rt < 2; ++rt) {
            int base = (w * 32 + rt * 16 + fr) * 64;
            aH[rt][0] = *(const short8v*)&Ah[base + ((s0 ^ r7) << 3)];
            aH[rt][1] = *(const short8v*)&Ah[base + (((s0 + 4) ^ r7) << 3)];
            aL[rt][0] = *(const short8v*)&Al[base + ((s0 ^ r7) << 3)];
            aL[rt][1] = *(const short8v*)&Al[base + (((s0 + 4) ^ r7) << 3)];
        }

        f32x4 acc[2][8];
#pragma unroll
        for (int rt = 0; rt < 2; ++rt)
#pragma unroll
            for (int js = 0; js < 8; ++js) acc[rt][js] = (f32x4){0.f, 0.f, 0.f, 0.f};

#pragma unroll
        for (int js = 0; js < 8; ++js) {
            int bbase = (js * 16 + fr) * 64;
            short8v bH0 = *(const short8v*)&Bh[bbase + ((s0 ^ r7) << 3)];
            short8v bH1 = *(const short8v*)&Bh[bbase + (((s0 + 4) ^ r7) << 3)];
            short8v bL0 = *(const short8v*)&Bl[bbase + ((s0 ^ r7) << 3)];
            short8v bL1 = *(const short8v*)&Bl[bbase + (((s0 + 4) ^ r7) << 3)];
#pragma unroll
            for (int rt = 0; rt < 2; ++rt) {
                f32x4 a = acc[rt][js];
                a = __builtin_amdgcn_mfma_f32_16x16x32_bf16(aH[rt][0], bH0, a, 0, 0, 0);
                a = __builtin_amdgcn_mfma_f32_16x16x32_bf16(aH[rt][1], bH1, a, 0, 0, 0);
                a = __builtin_amdgcn_mfma_f32_16x16x32_bf16(aH[rt][0], bL0, a, 0, 0, 0);
                a = __builtin_amdgcn_mfma_f32_16x16x32_bf16(aH[rt][1], bL1, a, 0, 0, 0);
                a = __builtin_amdgcn_mfma_f32_16x16x32_bf16(aL[rt][0], bH0, a, 0, 0, 0);
                a = __builtin_amdgcn_mfma_f32_16x16x32_bf16(aL[rt][1], bH1, a, 0, 0, 0);
                acc[rt][js] = a;
            }
        }

        // ---- pack with scaled threshold 0.5*n_i*n_j ----
#pragma unroll
        for (int rt = 0; rt < 2; ++rt) {
            int rb = w * 32 + rt * 16 + (l >> 4) * 4;
            float n0 = 0.5f * An[rb + 0];
            float n1 = 0.5f * An[rb + 1];
            float n2 = 0.5f * An[rb + 2];
            float n3 = 0.5f * An[rb + 3];
#pragma unroll
            for (int ws_ = 0; ws_ < 2; ++ws_) {
                unsigned long long w64 = 0;
#pragma unroll
                for (int js2 = 0; js2 < 4; ++js2) {
                    int js = ws_ * 4 + js2;
                    float nbv = Bn[js * 16 + (l & 15)];
                    f32x4 a = acc[rt][js];
                    unsigned long long c0 = __ballot(a[0] > n0 * nbv);
                    unsigned long long c1 = __ballot(a[1] > n1 * nbv);
                    unsigned long long c2 = __ballot(a[2] > n2 * nbv);
                    unsigned long long c3 = __ballot(a[3] > n3 * nbv);
                    unsigned long long sel = r == 0 ? c0 : r == 1 ? c1 : r == 2 ? c2 : c3;
                    w64 |= ((sel >> shift) & 0xFFFFULL) << (js2 * 16);
                }
                if (l < 16)
                    mask[(size_t)(i0 + w * 32 + rt * 16 + l) * 64 + bj * 2 + ws_] = w64;
            }
        }
        __syncthreads();                 // pack done before A restage
    }
}

// ---------------------------------------------------------------------------
// K3 (R11-verified): agg1(+bias+ReLU)+mm2+scores2, batch-paired.
// ---------------------------------------------------------------------------
__global__ __launch_bounds__(256) void agg1_fused_kernel(
        const float* __restrict__ h1, const float* __restrict__ ssrc,
        const float* __restrict__ sdst, const unsigned long long* __restrict__ mask,
        const float* __restrict__ b1, const float* __restrict__ W2,
        const float* __restrict__ a2s, const float* __restrict__ a2d,
        float* __restrict__ h2out, float* __restrict__ s2s, float* __restrict__ s2d) {
    int i = blockIdx.x * 4 + (threadIdx.x >> 6);   // node 0..4095
    int t = threadIdx.x & 63;
    int hh = t >> 4;

    float sdA = sdst[(size_t)i * 4 + hh];
    float sdB = sdst[(size_t)(i + N_NODES) * 4 + hh];
    unsigned long long myword = mask[(size_t)i * 64 + t];

    float mA = -1e30f, dA = 0.f, aA = 0.f;
    float mB = -1e30f, dB = 0.f, aB = 0.f;
    unsigned long long nz = __ballot(myword != 0ULL);
    while (nz) {
        int lw = __ffsll(nz) - 1;
        nz &= nz - 1;
        unsigned long long wbits = __shfl(myword, lw);
        while (wbits) {
            int bpos = __ffsll(wbits) - 1;
            wbits &= wbits - 1;
            int j = (lw << 6) + bpos;
            float ssA = ssrc[(size_t)j * 4 + hh];
            float ssB = ssrc[(size_t)(j + N_NODES) * 4 + hh];
            float hvA = h1[(size_t)j * 64 + t];
            float hvB = h1[(size_t)(j + N_NODES) * 64 + t];
            float e = sdA + ssA;
            e = e > 0.f ? e : 0.2f * e;
            float mn = fmaxf(mA, e);
            float cf = __expf(mA - mn);
            float wg = __expf(e - mn);
            dA = dA * cf + wg;
            aA = aA * cf + wg * hvA;
            mA = mn;
            e = sdB + ssB;
            e = e > 0.f ? e : 0.2f * e;
            mn = fmaxf(mB, e);
            cf = __expf(mB - mn);
            wg = __expf(e - mn);
            dB = dB * cf + wg;
            aB = aB * cf + wg * hvB;
            mB = mn;
        }
    }
    float b1v = b1[t];
    float oA = fmaxf(aA / dA + b1v, 0.f);
    float oB = fmaxf(aB / dB + b1v, 0.f);

    // mm2 for both rows (lanes 32..63 duplicate 0..31)
    int l2 = t & 31;
    float acc2A = 0.f, acc2B = 0.f;
#pragma unroll
    for (int k = 0; k < 64; ++k) {
        float wk = W2[k * 32 + l2];
        acc2A += rl(oA, k) * wk;
        acc2B += rl(oB, k) * wk;
    }

    float a2sv = a2s[l2], a2dv = a2d[l2];
    float psA = acc2A * a2sv, pdA = acc2A * a2dv;
    float psB = acc2B * a2sv, pdB = acc2B * a2dv;
#pragma unroll
    for (int mm = 4; mm >= 1; mm >>= 1) {
        psA += __shfl_xor(psA, mm);
        pdA += __shfl_xor(pdA, mm);
        psB += __shfl_xor(psB, mm);
        pdB += __shfl_xor(pdB, mm);
    }
    if (t < 32) {
        h2out[(size_t)i * 32 + t] = acc2A;
        h2out[(size_t)(i + N_NODES) * 32 + t] = acc2B;
        if ((t & 7) == 0) {
            s2s[(size_t)i * 4 + (t >> 3)] = psA;
            s2d[(size_t)i * 4 + (t >> 3)] = pdA;
            s2s[(size_t)(i + N_NODES) * 4 + (t >> 3)] = psB;
            s2d[(size_t)(i + N_NODES) * 4 + (t >> 3)] = pdB;
        }
    }
}

// ---------------------------------------------------------------------------
// K4 (R11-verified): agg2, batch-paired -> d_out.
// ---------------------------------------------------------------------------
__global__ __launch_bounds__(256) void agg2_kernel(
        const float* __restrict__ hfeat, const float* __restrict__ ssrc,
        const float* __restrict__ sdst, const unsigned long long* __restrict__ mask,
        const float* __restrict__ bias, float* __restrict__ out) {
    int i = blockIdx.x * 4 + (threadIdx.x >> 6);   // node 0..4095
    int t = threadIdx.x & 63;
    int tt = t & 31;
    int hh = tt >> 3;

    float sdA = sdst[(size_t)i * 4 + hh];
    float sdB = sdst[(size_t)(i + N_NODES) * 4 + hh];
    unsigned long long myword = mask[(size_t)i * 64 + t];

    float mA = -1e30f, dA = 0.f, aA = 0.f;
    float mB = -1e30f, dB = 0.f, aB = 0.f;
    unsigned long long nz = __ballot(myword != 0ULL);
    while (nz) {
        int lw = __ffsll(nz) - 1;
        nz &= nz - 1;
        unsigned long long wbits = __shfl(myword, lw);
        while (wbits) {
            int bpos = __ffsll(wbits) - 1;
            wbits &= wbits - 1;
            int j = (lw << 6) + bpos;
            float ssA = ssrc[(size_t)j * 4 + hh];
            float ssB = ssrc[(size_t)(j + N_NODES) * 4 + hh];
            float hvA = hfeat[(size_t)j * 32 + tt];
            float hvB = hfeat[(size_t)(j + N_NODES) * 32 + tt];
            float e = sdA + ssA;
            e = e > 0.f ? e : 0.2f * e;
            float mn = fmaxf(mA, e);
            float cf = __expf(mA - mn);
            float wg = __expf(e - mn);
            dA = dA * cf + wg;
            aA = aA * cf + wg * hvA;
            mA = mn;
            e = sdB + ssB;
            e = e > 0.f ? e : 0.2f * e;
            mn = fmaxf(mB, e);
            cf = __expf(mB - mn);
            wg = __expf(e - mn);
            dB = dB * cf + wg;
            aB = aB * cf + wg * hvB;
            mB = mn;
        }
    }
    float bv = bias[tt];
    if (t < 32) {
        out[(size_t)i * 32 + tt] = aA / dA + bv;
        out[(size_t)(i + N_NODES) * 32 + tt] = aB / dB + bv;
    }
}

// ---------------------------------------------------------------------------
extern "C" void kernel_launch(void* const* d_in, const int* in_sizes, int n_in,
                              void* d_out, int out_size, void* d_ws, size_t ws_size,
                              hipStream_t stream) {
    const float* x   = (const float*)d_in[0];
    const float* emb = (const float*)d_in[1];
    const float* Wp  = (const float*)d_in[2];
    const float* bp  = (const float*)d_in[3];
    const float* W1  = (const float*)d_in[4];
    const float* a1s = (const float*)d_in[5];
    const float* a1d = (const float*)d_in[6];
    const float* b1  = (const float*)d_in[7];
    const float* W2  = (const float*)d_in[8];
    const float* a2s = (const float*)d_in[9];
    const float* a2d = (const float*)d_in[10];
    const float* b2  = (const float*)d_in[11];

    const int ROWS = BATCH * N_NODES;  // 8192

    char* w = (char*)d_ws;
    unsigned long long* mask = (unsigned long long*)w; w += (size_t)N_NODES * 64 * 8;
    float* h1  = (float*)w;                      w += (size_t)ROWS * 64 * 4;
    float* s1s = (float*)w;                      w += (size_t)ROWS * 4 * 4;
    float* s1d = (float*)w;                      w += (size_t)ROWS * 4 * 4;
    float* h2  = (float*)w;                      w += (size_t)ROWS * 32 * 4;
    float* s2s = (float*)w;                      w += (size_t)ROWS * 4 * 4;
    float* s2d = (float*)w;                      w += (size_t)ROWS * 4 * 4;

    k2_kernel<<<dim3(512), dim3(256), 0, stream>>>(
        emb, mask, x, Wp, bp, W1, a1s, a1d, h1, s1s, s1d);
    agg1_fused_kernel<<<dim3(N_NODES / 4), dim3(256), 0, stream>>>(
        h1, s1s, s1d, mask, b1, W2, a2s, a2d, h2, s2s, s2d);
    agg2_kernel<<<dim3(N_NODES / 4), dim3(256), 0, stream>>>(
        h2, s2s, s2d, mask, b2, (float*)d_out);
}

// Round 17
// 32.283 us; speedup vs baseline: 1.1233x; 1.0252x over previous
//
#include <hip/hip_runtime.h>
#include <hip/hip_bf16.h>
#include <stdint.h>

#define N_NODES 4096
#define BATCH 2

typedef __attribute__((ext_vector_type(8))) short short8v;
typedef __attribute__((ext_vector_type(4))) float f32x4;

static __device__ inline float bf2f(unsigned short b) {
    return __uint_as_float(((unsigned)b) << 16);
}
static __device__ inline float rl(float v, int k) {   // wave-uniform broadcast
    return __uint_as_float(__builtin_amdgcn_readlane(__float_as_uint(v), k));
}

// Split 2 floats into bf16 hi (RNE) + bf16 lo (residual), packed as u32s.
static __device__ inline void cvt2(float f0, float f1, unsigned* hi, unsigned* lo) {
    float2 p;
    p.x = f0;
    p.y = f1;
    __hip_bfloat162 h = __float22bfloat162_rn(p);
    unsigned hb;
    __builtin_memcpy(&hb, &h, 4);
    p.x = f0 - bf2f((unsigned short)hb);
    p.y = f1 - bf2f((unsigned short)(hb >> 16));
    __hip_bfloat162 l2v = __float22bfloat162_rn(p);
    unsigned lb;
    __builtin_memcpy(&lb, &l2v, 4);
    *hi = hb;
    *lo = lb;
}

struct PanelRegs {
    float4 r0[4], r1[4];
};

// LOAD phase: global fp32 panel rows -> registers (issues 8 dwordx4 loads).
static __device__ inline void load_panel(const float* __restrict__ emb, int g0,
                                         int row, int half, PanelRegs& R) {
#pragma unroll
    for (int q = 0; q < 4; ++q) {
        int slot = half * 4 + q;
        const float* pa = &emb[(size_t)(g0 + row) * 64 + slot * 8];
        R.r0[q] = *(const float4*)pa;
        R.r1[q] = *(const float4*)(pa + 4);
    }
}

// WRITE phase: regs -> split-bf16 swizzled LDS + row norm. (R15 layout/order.)
static __device__ inline void write_panel(const PanelRegs& R, unsigned short* H,
                                          unsigned short* L, float* Nrm,
                                          int row, int half) {
    float n = 0.f;
#pragma unroll
    for (int q = 0; q < 4; ++q) {
        int slot = half * 4 + q;
        float4 a0 = R.r0[q];
        float4 a1 = R.r1[q];
        n += a0.x * a0.x + a0.y * a0.y + a0.z * a0.z + a0.w * a0.w +
             a1.x * a1.x + a1.y * a1.y + a1.z * a1.z + a1.w * a1.w;
        union {
            unsigned u[4];
            short8v v;
        } HH, LL;
        cvt2(a0.x, a0.y, &HH.u[0], &LL.u[0]);
        cvt2(a0.z, a0.w, &HH.u[1], &LL.u[1]);
        cvt2(a1.x, a1.y, &HH.u[2], &LL.u[2]);
        cvt2(a1.z, a1.w, &HH.u[3], &LL.u[3]);
        int ss = ((slot ^ (row & 7)) << 3);
        *(short8v*)&H[row * 64 + ss] = HH.v;
        *(short8v*)&L[row * 64 + ss] = LL.v;
    }
    n += __shfl_xor(n, 1);
    if (half == 0) Nrm[row] = sqrtf(n);
}

// ---------------------------------------------------------------------------
// K2 fat kernel: blocks [0,256) feat1; blocks [256,512) adjacency 4-TILE
// with T14 async-split pipeline: LOAD A(p+1) issues after the barrier and
// drains under MFMA+pack of panel p. B staged once.
// Threshold scaled per (row,col): dot_raw > 0.5 * n_i * n_j.
// ---------------------------------------------------------------------------
__global__ __launch_bounds__(256) void k2_kernel(
        const float* __restrict__ emb, unsigned long long* __restrict__ mask,
        const float* __restrict__ x, const float* __restrict__ Wp,
        const float* __restrict__ bp, const float* __restrict__ W1,
        const float* __restrict__ a1s, const float* __restrict__ a1d,
        float* __restrict__ h1out, float* __restrict__ ssrc, float* __restrict__ sdst) {
    __shared__ unsigned short Ah[128 * 64];
    __shared__ unsigned short Al[128 * 64];
    __shared__ unsigned short Bh[128 * 64];
    __shared__ unsigned short Bl[128 * 64];
    __shared__ float An[128];
    __shared__ float Bn[128];
    int t = threadIdx.x;
    int w = t >> 6, l = t & 63;

    if (blockIdx.x < 256) {
        // ================= feat1: proj + mm1 + scores1 (R5-verified) =======
        int b = blockIdx.x;
        int row0 = b * 32 + w * 8;

        float xv[8];
#pragma unroll
        for (int r = 0; r < 8; ++r) xv[r] = x[(size_t)(row0 + r) * 16 + (l & 15)];

        float h0[8];
        float bpv = bp[l];
#pragma unroll
        for (int r = 0; r < 8; ++r) h0[r] = bpv;
#pragma unroll
        for (int k = 0; k < 16; ++k) {
            float wk = Wp[k * 64 + l];
#pragma unroll
            for (int r = 0; r < 8; ++r) h0[r] += rl(xv[r], k) * wk;
        }

        float h1[8] = {0.f, 0.f, 0.f, 0.f, 0.f, 0.f, 0.f, 0.f};
#pragma unroll
        for (int k = 0; k < 64; ++k) {
            float wk = W1[k * 64 + l];
#pragma unroll
            for (int r = 0; r < 8; ++r) h1[r] += rl(h0[r], k) * wk;
        }

        float as_ = a1s[l], ad_ = a1d[l];
#pragma unroll
        for (int r = 0; r < 8; ++r) {
            h1out[(size_t)(row0 + r) * 64 + l] = h1[r];
            float ps = h1[r] * as_, pd = h1[r] * ad_;
#pragma unroll
            for (int m = 8; m >= 1; m >>= 1) {
                ps += __shfl_xor(ps, m);
                pd += __shfl_xor(pd, m);
            }
            if ((l & 15) == 0) {
                ssrc[(size_t)(row0 + r) * 4 + (l >> 4)] = ps;
                sdst[(size_t)(row0 + r) * 4 + (l >> 4)] = pd;
            }
        }
        return;
    }

    // ================= adjacency: 4 i-panels x 1 j-panel, pipelined ========
    int tile4 = blockIdx.x - 256;        // 0..255
    int bi4 = tile4 >> 5;                // 0..7
    int bj = tile4 & 31;
    int j0 = bj * 128;

    int rhalf = l >> 1, half = l & 1;
    int srow = w * 32 + rhalf;           // staging row 0..127

    {   // B staged once (load+write back-to-back; one-time cost)
        PanelRegs RB;
        load_panel(emb, j0, srow, half, RB);
        write_panel(RB, Bh, Bl, Bn, srow, half);
    }

    PanelRegs RA;
    load_panel(emb, bi4 * 512, srow, half, RA);   // A(0)

    int fr = l & 15;
    int s0 = l >> 4;                     // k-slot 0..3
    int r7 = l & 7;
    int shift = ((l & 15) >> 2) * 16;
    int r = l & 3;

#pragma unroll 1
    for (int p = 0; p < 4; ++p) {
        int i0 = (bi4 * 4 + p) * 128;
        write_panel(RA, Ah, Al, An, srow, half);
        __syncthreads();                 // A(p) (+B on p=0) visible

        if (p < 3) load_panel(emb, i0 + 128, srow, half, RA);  // prefetch A(p+1)

        // ---- A fragments (R5-verified reader) ----
        short8v aH[2][2], aL[2][2];
#pragma unroll
        for (int rt = 0; rt < 2; ++rt) {
            int base = (w * 32 + rt * 16 + fr) * 64;
            aH[rt][0] = *(const short8v*)&Ah[base + ((s0 ^ r7) << 3)];
            aH[rt][1] = *(const short8v*)&Ah[base + (((s0 + 4) ^ r7) << 3)];
            aL[rt][0] = *(const short8v*)&Al[base + ((s0 ^ r7) << 3)];
            aL[rt][1] = *(const short8v*)&Al[base + (((s0 + 4) ^ r7) << 3)];
        }

        f32x4 acc[2][8];
#pragma unroll
        for (int rt = 0; rt < 2; ++rt)
#pragma unroll
            for (int js = 0; js < 8; ++js) acc[rt][js] = (f32x4){0.f, 0.f, 0.f, 0.f};

#pragma unroll
        for (int js = 0; js < 8; ++js) {
            int bbase = (js * 16 + fr) * 64;
            short8v bH0 = *(const short8v*)&Bh[bbase + ((s0 ^ r7) << 3)];
            short8v bH1 = *(const short8v*)&Bh[bbase + (((s0 + 4) ^ r7) << 3)];
            short8v bL0 = *(const short8v*)&Bl[bbase + ((s0 ^ r7) << 3)];
            short8v bL1 = *(const short8v*)&Bl[bbase + (((s0 + 4) ^ r7) << 3)];
#pragma unroll
            for (int rt = 0; rt < 2; ++rt) {
                f32x4 a = acc[rt][js];
                a = __builtin_amdgcn_mfma_f32_16x16x32_bf16(aH[rt][0], bH0, a, 0, 0, 0);
                a = __builtin_amdgcn_mfma_f32_16x16x32_bf16(aH[rt][1], bH1, a, 0, 0, 0);
                a = __builtin_amdgcn_mfma_f32_16x16x32_bf16(aH[rt][0], bL0, a, 0, 0, 0);
                a = __builtin_amdgcn_mfma_f32_16x16x32_bf16(aH[rt][1], bL1, a, 0, 0, 0);
                a = __builtin_amdgcn_mfma_f32_16x16x32_bf16(aL[rt][0], bH0, a, 0, 0, 0);
                a = __builtin_amdgcn_mfma_f32_16x16x32_bf16(aL[rt][1], bH1, a, 0, 0, 0);
                acc[rt][js] = a;
            }
        }

        // ---- pack with scaled threshold 0.5*n_i*n_j ----
#pragma unroll
        for (int rt = 0; rt < 2; ++rt) {
            int rb = w * 32 + rt * 16 + (l >> 4) * 4;
            float n0 = 0.5f * An[rb + 0];
            float n1 = 0.5f * An[rb + 1];
            float n2 = 0.5f * An[rb + 2];
            float n3 = 0.5f * An[rb + 3];
#pragma unroll
            for (int ws_ = 0; ws_ < 2; ++ws_) {
                unsigned long long w64 = 0;
#pragma unroll
                for (int js2 = 0; js2 < 4; ++js2) {
                    int js = ws_ * 4 + js2;
                    float nbv = Bn[js * 16 + (l & 15)];
                    f32x4 a = acc[rt][js];
                    unsigned long long c0 = __ballot(a[0] > n0 * nbv);
                    unsigned long long c1 = __ballot(a[1] > n1 * nbv);
                    unsigned long long c2 = __ballot(a[2] > n2 * nbv);
                    unsigned long long c3 = __ballot(a[3] > n3 * nbv);
                    unsigned long long sel = r == 0 ? c0 : r == 1 ? c1 : r == 2 ? c2 : c3;
                    w64 |= ((sel >> shift) & 0xFFFFULL) << (js2 * 16);
                }
                if (l < 16)
                    mask[(size_t)(i0 + w * 32 + rt * 16 + l) * 64 + bj * 2 + ws_] = w64;
            }
        }
        __syncthreads();                 // pack done before A restage
    }
}

// ---------------------------------------------------------------------------
// K3 (R11-verified): agg1(+bias+ReLU)+mm2+scores2, batch-paired.
// ---------------------------------------------------------------------------
__global__ __launch_bounds__(256) void agg1_fused_kernel(
        const float* __restrict__ h1, const float* __restrict__ ssrc,
        const float* __restrict__ sdst, const unsigned long long* __restrict__ mask,
        const float* __restrict__ b1, const float* __restrict__ W2,
        const float* __restrict__ a2s, const float* __restrict__ a2d,
        float* __restrict__ h2out, float* __restrict__ s2s, float* __restrict__ s2d) {
    int i = blockIdx.x * 4 + (threadIdx.x >> 6);   // node 0..4095
    int t = threadIdx.x & 63;
    int hh = t >> 4;

    float sdA = sdst[(size_t)i * 4 + hh];
    float sdB = sdst[(size_t)(i + N_NODES) * 4 + hh];
    unsigned long long myword = mask[(size_t)i * 64 + t];

    float mA = -1e30f, dA = 0.f, aA = 0.f;
    float mB = -1e30f, dB = 0.f, aB = 0.f;
    unsigned long long nz = __ballot(myword != 0ULL);
    while (nz) {
        int lw = __ffsll(nz) - 1;
        nz &= nz - 1;
        unsigned long long wbits = __shfl(myword, lw);
        while (wbits) {
            int bpos = __ffsll(wbits) - 1;
            wbits &= wbits - 1;
            int j = (lw << 6) + bpos;
            float ssA = ssrc[(size_t)j * 4 + hh];
            float ssB = ssrc[(size_t)(j + N_NODES) * 4 + hh];
            float hvA = h1[(size_t)j * 64 + t];
            float hvB = h1[(size_t)(j + N_NODES) * 64 + t];
            float e = sdA + ssA;
            e = e > 0.f ? e : 0.2f * e;
            float mn = fmaxf(mA, e);
            float cf = __expf(mA - mn);
            float wg = __expf(e - mn);
            dA = dA * cf + wg;
            aA = aA * cf + wg * hvA;
            mA = mn;
            e = sdB + ssB;
            e = e > 0.f ? e : 0.2f * e;
            mn = fmaxf(mB, e);
            cf = __expf(mB - mn);
            wg = __expf(e - mn);
            dB = dB * cf + wg;
            aB = aB * cf + wg * hvB;
            mB = mn;
        }
    }
    float b1v = b1[t];
    float oA = fmaxf(aA / dA + b1v, 0.f);
    float oB = fmaxf(aB / dB + b1v, 0.f);

    // mm2 for both rows (lanes 32..63 duplicate 0..31)
    int l2 = t & 31;
    float acc2A = 0.f, acc2B = 0.f;
#pragma unroll
    for (int k = 0; k < 64; ++k) {
        float wk = W2[k * 32 + l2];
        acc2A += rl(oA, k) * wk;
        acc2B += rl(oB, k) * wk;
    }

    float a2sv = a2s[l2], a2dv = a2d[l2];
    float psA = acc2A * a2sv, pdA = acc2A * a2dv;
    float psB = acc2B * a2sv, pdB = acc2B * a2dv;
#pragma unroll
    for (int mm = 4; mm >= 1; mm >>= 1) {
        psA += __shfl_xor(psA, mm);
        pdA += __shfl_xor(pdA, mm);
        psB += __shfl_xor(psB, mm);
        pdB += __shfl_xor(pdB, mm);
    }
    if (t < 32) {
        h2out[(size_t)i * 32 + t] = acc2A;
        h2out[(size_t)(i + N_NODES) * 32 + t] = acc2B;
        if ((t & 7) == 0) {
            s2s[(size_t)i * 4 + (t >> 3)] = psA;
            s2d[(size_t)i * 4 + (t >> 3)] = pdA;
            s2s[(size_t)(i + N_NODES) * 4 + (t >> 3)] = psB;
            s2d[(size_t)(i + N_NODES) * 4 + (t >> 3)] = pdB;
        }
    }
}

// ---------------------------------------------------------------------------
// K4 (R11-verified): agg2, batch-paired -> d_out.
// ---------------------------------------------------------------------------
__global__ __launch_bounds__(256) void agg2_kernel(
        const float* __restrict__ hfeat, const float* __restrict__ ssrc,
        const float* __restrict__ sdst, const unsigned long long* __restrict__ mask,
        const float* __restrict__ bias, float* __restrict__ out) {
    int i = blockIdx.x * 4 + (threadIdx.x >> 6);   // node 0..4095
    int t = threadIdx.x & 63;
    int tt = t & 31;
    int hh = tt >> 3;

    float sdA = sdst[(size_t)i * 4 + hh];
    float sdB = sdst[(size_t)(i + N_NODES) * 4 + hh];
    unsigned long long myword = mask[(size_t)i * 64 + t];

    float mA = -1e30f, dA = 0.f, aA = 0.f;
    float mB = -1e30f, dB = 0.f, aB = 0.f;
    unsigned long long nz = __ballot(myword != 0ULL);
    while (nz) {
        int lw = __ffsll(nz) - 1;
        nz &= nz - 1;
        unsigned long long wbits = __shfl(myword, lw);
        while (wbits) {
            int bpos = __ffsll(wbits) - 1;
            wbits &= wbits - 1;
            int j = (lw << 6) + bpos;
            float ssA = ssrc[(size_t)j * 4 + hh];
            float ssB = ssrc[(size_t)(j + N_NODES) * 4 + hh];
            float hvA = hfeat[(size_t)j * 32 + tt];
            float hvB = hfeat[(size_t)(j + N_NODES) * 32 + tt];
            float e = sdA + ssA;
            e = e > 0.f ? e : 0.2f * e;
            float mn = fmaxf(mA, e);
            float cf = __expf(mA - mn);
            float wg = __expf(e - mn);
            dA = dA * cf + wg;
            aA = aA * cf + wg * hvA;
            mA = mn;
            e = sdB + ssB;
            e = e > 0.f ? e : 0.2f * e;
            mn = fmaxf(mB, e);
            cf = __expf(mB - mn);
            wg = __expf(e - mn);
            dB = dB * cf + wg;
            aB = aB * cf + wg * hvB;
            mB = mn;
        }
    }
    float bv = bias[tt];
    if (t < 32) {
        out[(size_t)i * 32 + tt] = aA / dA + bv;
        out[(size_t)(i + N_NODES) * 32 + tt] = aB / dB + bv;
    }
}

// ---------------------------------------------------------------------------
extern "C" void kernel_launch(void* const* d_in, const int* in_sizes, int n_in,
                              void* d_out, int out_size, void* d_ws, size_t ws_size,
                              hipStream_t stream) {
    const float* x   = (const float*)d_in[0];
    const float* emb = (const float*)d_in[1];
    const float* Wp  = (const float*)d_in[2];
    const float* bp  = (const float*)d_in[3];
    const float* W1  = (const float*)d_in[4];
    const float* a1s = (const float*)d_in[5];
    const float* a1d = (const float*)d_in[6];
    const float* b1  = (const float*)d_in[7];
    const float* W2  = (const float*)d_in[8];
    const float* a2s = (const float*)d_in[9];
    const float* a2d = (const float*)d_in[10];
    const float* b2  = (const float*)d_in[11];

    const int ROWS = BATCH * N_NODES;  // 8192

    char* w = (char*)d_ws;
    unsigned long long* mask = (unsigned long long*)w; w += (size_t)N_NODES * 64 * 8;
    float* h1  = (float*)w;                      w += (size_t)ROWS * 64 * 4;
    float* s1s = (float*)w;                      w += (size_t)ROWS * 4 * 4;
    float* s1d = (float*)w;                      w += (size_t)ROWS * 4 * 4;
    float* h2  = (float*)w;                      w += (size_t)ROWS * 32 * 4;
    float* s2s = (float*)w;                      w += (size_t)ROWS * 4 * 4;
    float* s2d = (float*)w;                      w += (size_t)ROWS * 4 * 4;

    k2_kernel<<<dim3(512), dim3(256), 0, stream>>>(
        emb, mask, x, Wp, bp, W1, a1s, a1d, h1, s1s, s1d);
    agg1_fused_kernel<<<dim3(N_NODES / 4), dim3(256), 0, stream>>>(
        h1, s1s, s1d, mask, b1, W2, a2s, a2d, h2, s2s, s2d);
    agg2_kernel<<<dim3(N_NODES / 4), dim3(256), 0, stream>>>(
        h2, s2s, s2d, mask, b2, (float*)d_out);
}